// Round 13
// baseline (31066.595 us; speedup 1.0000x reference)
//
#include <hip/hip_runtime.h>
#include <hip/hip_fp16.h>
#include <stdint.h>

#define SEQ_LEN 16384
#define H       512
#define NWG     32      // WG k owns h[16k..16k+16)
#define HK      16
#define T       512
#define NR      48      // rows per matrix per WG (3 gates x 16)
#define WPITCH  257     // uint32 pitch per weight row (256 data + 1 pad)

typedef unsigned long long u64;
typedef _Float16 h2 __attribute__((ext_vector_type(2)));
typedef unsigned int u32x4 __attribute__((ext_vector_type(4)));

#define LD_AG(p)   __hip_atomic_load((p),      __ATOMIC_RELAXED, __HIP_MEMORY_SCOPE_AGENT)
#define ST_AG(p,v) __hip_atomic_store((p),(v), __ATOMIC_RELAXED, __HIP_MEMORY_SCOPE_AGENT)

__device__ __forceinline__ h2 as_h2(uint32_t u) {
    union { uint32_t u; h2 h; } c; c.u = u; return c.h;
}

#if defined(__has_builtin)
#if __has_builtin(__builtin_amdgcn_fdot2)
#define FDOT2(a, b, c) __builtin_amdgcn_fdot2((a), (b), (c), false)
#endif
#endif
#ifndef FDOT2
__device__ __forceinline__ float fdot2_sw(h2 a, h2 b, float c) {
    return fmaf((float)a.x, (float)b.x, fmaf((float)a.y, (float)b.y, c));
}
#define FDOT2(a, b, c) fdot2_sw((a), (b), (c))
#endif

__device__ __forceinline__ uint32_t pk2(float a, float b) {
    return (uint32_t)__half_as_ushort(__float2half(a)) |
           ((uint32_t)__half_as_ushort(__float2half(b)) << 16);
}

// 32B poll: two dwordx4, L1/L2-bypassed, both in flight (parallel RTT)
__device__ __forceinline__ void poll32(const uint32_t* p, u32x4& a, u32x4& b) {
    asm volatile("global_load_dwordx4 %0, %2, off sc0 sc1\n\t"
                 "global_load_dwordx4 %1, %3, off sc0 sc1\n\t"
                 "s_waitcnt vmcnt(0)"
                 : "=v"(a), "=v"(b) : "v"(p), "v"(p + 4) : "memory");
}

// wire format: 8 u32 words per WG slot = 16 f16 values; each f16's mantissa LSB
// is the phase bit ((step>>1)&1). Slot parity = step&1, so consecutive occupants
// of a slot (steps t and t+2) always differ in phase bit -> self-validating.
__global__ void gru_init(uint32_t* __restrict__ tag32, int wgStride, int parOff) {
    int i = threadIdx.x;                          // 512 threads, 1 block
    if (i < 512) {
        int wg = i >> 4, rem = i & 15, par = rem >> 3, k = rem & 7;
        // par0: h0 = +0.0, phase 0 (valid for t=0); par1: phase 1 (invalid for t=1)
        ST_AG(&tag32[(size_t)wg * wgStride + (size_t)par * parOff + k],
              par ? 0x00010001u : 0u);
    }
}

__launch_bounds__(T, 1)
__global__ void gru_main(const float* __restrict__ x,
                         const float* __restrict__ Wih,
                         const float* __restrict__ Whh,
                         const float* __restrict__ bih,
                         const float* __restrict__ bhh,
                         float* __restrict__ out,
                         uint32_t* __restrict__ tag32,
                         int wgStride, int parOff)
{
    const int wg  = blockIdx.x;
    const int tid = threadIdx.x;
    const int j0  = wg * HK;

    __shared__ uint32_t w_lds[2 * NR * WPITCH];  // rows 0..47 W_ih, 48..95 W_hh (f16 pairs)
    __shared__ uint32_t x_u[2][H / 2];           // packed f16x2 x
    __shared__ uint32_t h_u[2][H / 2];           // packed f16x2 h
    __shared__ float    sums_g[2][NR];
    __shared__ float    sums_h[2][NR];
    __shared__ float    bsum_g[NR];
    __shared__ float    bsum_h[NR];

    __half* wh = (__half*)w_lds;                 // half pitch = 2*WPITCH

    // ---- prologue: stage weights f32 -> f16 LDS ----
    for (int idx = tid; idx < 2 * NR * H; idx += T) {
        int r  = idx >> 9;                       // 0..95
        int k  = idx & (H - 1);
        int rr = (r < NR) ? r : r - NR;
        int g  = rr >> 4;
        int jj = rr & 15;
        int grow = g * H + j0 + jj;
        float w = (r < NR) ? Wih[(size_t)grow * H + k] : Whh[(size_t)grow * H + k];
        wh[r * (2 * WPITCH) + k] = __float2half(w);
    }
    if (tid < NR) {
        int g  = tid >> 4;
        int jj = tid & 15;
        int grow = g * H + j0 + jj;
        bsum_g[tid] = (g == 2) ? bih[grow] : (bih[grow] + bhh[grow]);
        bsum_h[tid] = (g == 2) ? bhh[grow] : 0.0f;
    }
    if (tid >= 64 && tid < 128) {                // wave 1 prefills x_0 (packed f16)
        int p1 = tid - 64;
        float4 xa = ((const float4*)x)[2 * p1];
        float4 xb = ((const float4*)x)[2 * p1 + 1];
        ((uint4*)x_u[0])[p1] = make_uint4(pk2(xa.x, xa.y), pk2(xa.z, xa.w),
                                          pk2(xb.x, xb.y), pk2(xb.z, xb.w));
    }
    __syncthreads();

    // dot-thread mapping (waves 2..7): row 0..47, chunk 0..7
    const int idxd = tid - 128;
    const int row  = idxd >> 3;                  // 0..47
    const int c8   = idxd & 7;                   // == tid&7

    // ---- W_hh into registers, pre-staggered so loop indices are static ----
    uint32_t wreg[32];
    if (tid >= 128) {
        const uint32_t* wr = w_lds + (NR + row) * WPITCH + c8 * 32;
        #pragma unroll
        for (int i = 0; i < 32; ++i) wreg[i] = wr[(i + 4 * c8) & 31];
    }
    __syncthreads();

    float4 xpa = {0,0,0,0}, xpb = {0,0,0,0};     // wave 1: x_{t+1} payload
    if (tid >= 64 && tid < 128) {
        int p1 = tid - 64;
        xpa = ((const float4*)(x + H))[2 * p1];
        xpb = ((const float4*)(x + H))[2 * p1 + 1];
    }
    float hprev = 0.0f;                          // own h (wave-2 lanes 0..15)

    for (int t = 0; t < SEQ_LEN; ++t) {
        const int par = t & 1, nxt = par ^ 1;
        float4 xna = xpa, xnb = xpb;             // default carry

        if (tid < 32) {
            // ---- poller tid watches WG tid's 32B slot (2 loads in flight) ----
            const uint32_t fm = (uint32_t)((t >> 1) & 1) * 0x00010001u;
            const uint32_t* base = tag32 + (size_t)tid * wgStride + (size_t)par * parOff;
            u32x4 a, b;
            poll32(base, a, b);
            while (((a[0] ^ fm) | (a[1] ^ fm) | (a[2] ^ fm) | (a[3] ^ fm) |
                    (b[0] ^ fm) | (b[1] ^ fm) | (b[2] ^ fm) | (b[3] ^ fm)) & 0x00010001u)
                poll32(base, a, b);
            // words ARE the packed f16x2 LDS format -> direct store, no repack
            ((uint4*)&h_u[par][tid * 8])[0]     = make_uint4(a[0], a[1], a[2], a[3]);
            ((uint4*)&h_u[par][tid * 8 + 4])[0] = make_uint4(b[0], b[1], b[2], b[3]);
        } else if (tid >= 64 && tid < 128) {
            // wave 1: issue x_{t+2} prefetch (latency hidden under others' spin)
            int tq = t + 2; if (tq >= SEQ_LEN) tq = SEQ_LEN - 1;
            int p1 = tid - 64;
            xna = ((const float4*)(x + (size_t)tq * H))[2 * p1];
            xnb = ((const float4*)(x + (size_t)tq * H))[2 * p1 + 1];
        } else if (tid >= 128) {
            // ---- gi dots over x_u[par] (weights from LDS, fdot2) ----
            const uint32_t* gw = w_lds + row * WPITCH + c8 * 32;
            const uint32_t* B  = &x_u[par][c8 * 32];
            float acc = 0.0f;
            #pragma unroll
            for (int i = 0; i < 32; ++i) {
                int s = (i + 4 * c8) & 31;
                acc = FDOT2(as_h2(gw[s]), as_h2(B[s]), acc);
            }
            acc += __shfl_xor(acc, 1);
            acc += __shfl_xor(acc, 2);
            acc += __shfl_xor(acc, 4);
            if (c8 == 0) sums_g[par][row] = acc + bsum_g[row];
        }
        __syncthreads();   // A: h_u[par] + sums_g[par] ready; x_u[par] consumed

        if (tid >= 64 && tid < 128) {
            int p1 = tid - 64;
            ((uint4*)x_u[nxt])[p1] = make_uint4(pk2(xpa.x, xpa.y), pk2(xpa.z, xpa.w),
                                                pk2(xpb.x, xpb.y), pk2(xpb.z, xpb.w));
            xpa = xna; xpb = xnb;                // advance pipeline AFTER commit
        } else if (tid >= 128) {
            // ---- hh dots over h_u[par] (weights from registers, fdot2) ----
            const uint32_t* B = &h_u[par][c8 * 32];
            float acc = 0.0f;
            #pragma unroll
            for (int i = 0; i < 32; ++i) {
                int s = (i + 4 * c8) & 31;
                acc = FDOT2(as_h2(wreg[i]), as_h2(B[s]), acc);
            }
            acc += __shfl_xor(acc, 1);
            acc += __shfl_xor(acc, 2);
            acc += __shfl_xor(acc, 4);
            if (c8 == 0) sums_h[par][row] = acc + bsum_h[row];
        }
        __syncthreads();   // B: sums_h[par] + x_u[nxt] ready

        if (tid >= 128 && tid < 192) {
            // ---- gates + publish: wave 2 (lanes 0..15 compute; 4 lanes store u64) ----
            int lane = tid & 63;
            uint32_t pk16 = 0;
            float hnew = 0.0f;
            if (lane < 16) {
                float sg0 = sums_g[par][lane],      sg1 = sums_g[par][16 + lane], sg2 = sums_g[par][32 + lane];
                float sh0 = sums_h[par][lane],      sh1 = sums_h[par][16 + lane], sh2 = sums_h[par][32 + lane];
                float r_ = 1.0f / (1.0f + __expf(-(sg0 + sh0)));
                float z_ = 1.0f / (1.0f + __expf(-(sg1 + sh1)));
                float a  = sg2 + r_ * sh2;
                a = fminf(12.0f, fmaxf(-12.0f, a));
                float e2 = __expf(2.0f * a);
                float n_ = (e2 - 1.0f) / (e2 + 1.0f);
                hnew = (1.0f - z_) * n_ + z_ * hprev;
                hprev = hnew;
                pk16 = ((uint32_t)__half_as_ushort(__float2half(hnew)) & 0xFFFEu)
                     | (uint32_t)(((t + 1) >> 1) & 1);
            }
            uint32_t w = pk16 | (__shfl(pk16, lane + 1) << 16);      // even lanes: pair
            u64 q = (u64)w | ((u64)__shfl(w, lane + 2) << 32);       // lanes 0,4,8,12: quad
            if (lane < 16 && (lane & 3) == 0) {
                u64* pb = (u64*)(tag32 + (size_t)wg * wgStride + (size_t)nxt * parOff) + (lane >> 2);
                ST_AG(pb, q);
            }
            if (lane < 16) out[(size_t)t * H + j0 + lane] = hnew;    // off critical path
        }
        // no barrier C (champion structure): parity double-buffering + barrier A
        // of step t+1 separate all LDS reuse (audited pairwise).
    }
}

extern "C" void kernel_launch(void* const* d_in, const int* in_sizes, int n_in,
                              void* d_out, int out_size, void* d_ws, size_t ws_size,
                              hipStream_t stream) {
    const float* x   = (const float*)d_in[0];
    const float* Wih = (const float*)d_in[1];
    const float* Whh = (const float*)d_in[2];
    const float* bih = (const float*)d_in[3];
    const float* bhh = (const float*)d_in[4];
    float* out = (float*)d_out;
    uint32_t* tag32 = (uint32_t*)d_ws;

    // scatter WG slots 1KB apart if workspace allows (32 KB), else compact 2 KB
    int wgStride = 256, parOff = 64;
    if (ws_size < 33 * 1024) { wgStride = 16; parOff = 8; }

    gru_init<<<1, 512, 0, stream>>>(tag32, wgStride, parOff);
    gru_main<<<NWG, T, 0, stream>>>(x, Wih, Whh, bih, bhh, out, tag32, wgStride, parOff);
}

// Round 15
// 27708.655 us; speedup vs baseline: 1.1212x; 1.1212x over previous
//
#include <hip/hip_runtime.h>
#include <hip/hip_fp16.h>
#include <stdint.h>

#define SEQ_LEN 16384
#define H       512
#define NWG     32      // WG k owns h[16k..16k+16)
#define HK      16
#define T       512
#define NR      48      // rows per matrix per WG (3 gates x 16)
#define WPITCH  257     // uint32 pitch per weight row (256 data + 1 pad)

typedef unsigned long long u64;
typedef _Float16 h2 __attribute__((ext_vector_type(2)));
typedef unsigned int u32x4 __attribute__((ext_vector_type(4)));

#define LD_AG(p)   __hip_atomic_load((p),      __ATOMIC_RELAXED, __HIP_MEMORY_SCOPE_AGENT)
#define ST_AG(p,v) __hip_atomic_store((p),(v), __ATOMIC_RELAXED, __HIP_MEMORY_SCOPE_AGENT)

__device__ __forceinline__ h2 as_h2(uint32_t u) {
    union { uint32_t u; h2 h; } c; c.u = u; return c.h;
}

#if defined(__has_builtin)
#if __has_builtin(__builtin_amdgcn_fdot2)
#define FDOT2(a, b, c) __builtin_amdgcn_fdot2((a), (b), (c), false)
#endif
#endif
#ifndef FDOT2
__device__ __forceinline__ float fdot2_sw(h2 a, h2 b, float c) {
    return fmaf((float)a.x, (float)b.x, fmaf((float)a.y, (float)b.y, c));
}
#define FDOT2(a, b, c) fdot2_sw((a), (b), (c))
#endif

__device__ __forceinline__ uint32_t pk2(float a, float b) {
    return (uint32_t)__half_as_ushort(__float2half(a)) |
           ((uint32_t)__half_as_ushort(__float2half(b)) << 16);
}

// champion 16B poll: one dwordx4, L1/L2-bypassed, dependent spin (PROVEN)
__device__ __forceinline__ u32x4 poll16(const uint32_t* p) {
    u32x4 v;
    asm volatile("global_load_dwordx4 %0, %1, off sc0 sc1\n\t"
                 "s_waitcnt vmcnt(0)"
                 : "=v"(v) : "v"(p) : "memory");
    return v;
}

// exchange word: [f16 value (hi 16) | step tag (lo 16)]
__global__ void gru_init(uint32_t* __restrict__ tag32) {
    int i = blockIdx.x * blockDim.x + threadIdx.x;
    if (i < H)            ST_AG(&tag32[i], 0u);        // h0 = 0, tag 0
    else if (i < 2 * H)   ST_AG(&tag32[i], 0xFFFFu);   // invalid tag
}

__launch_bounds__(T, 1)
__global__ void gru_main(const float* __restrict__ x,
                         const float* __restrict__ Wih,
                         const float* __restrict__ Whh,
                         const float* __restrict__ bih,
                         const float* __restrict__ bhh,
                         float* __restrict__ out,
                         uint32_t* __restrict__ tag32)
{
    const int wg  = blockIdx.x;
    const int tid = threadIdx.x;
    const int j0  = wg * HK;

    __shared__ uint32_t w_lds[2 * NR * WPITCH];  // rows 0..47 W_ih, 48..95 W_hh (f16 pairs)
    __shared__ uint32_t x_u[2][H / 2];           // packed f16x2 x
    __shared__ uint32_t h_u[2][H / 2];           // packed f16x2 h
    __shared__ float    sums_g[2][NR];
    __shared__ float    sums_h[2][NR];
    __shared__ float    bsum_g[NR];
    __shared__ float    bsum_h[NR];
    __shared__ uint32_t ccnt[8];                 // per-chunk ready counters (monotonic)

    __half* wh = (__half*)w_lds;                 // half pitch = 2*WPITCH

    // ---- prologue: stage weights f32 -> f16 LDS ----
    for (int idx = tid; idx < 2 * NR * H; idx += T) {
        int r  = idx >> 9;                       // 0..95
        int k  = idx & (H - 1);
        int rr = (r < NR) ? r : r - NR;
        int g  = rr >> 4;
        int jj = rr & 15;
        int grow = g * H + j0 + jj;
        float w = (r < NR) ? Wih[(size_t)grow * H + k] : Whh[(size_t)grow * H + k];
        wh[r * (2 * WPITCH) + k] = __float2half(w);
    }
    if (tid < NR) {
        int g  = tid >> 4;
        int jj = tid & 15;
        int grow = g * H + j0 + jj;
        bsum_g[tid] = (g == 2) ? bih[grow] : (bih[grow] + bhh[grow]);
        bsum_h[tid] = (g == 2) ? bhh[grow] : 0.0f;
    }
    if (tid < 8) ccnt[tid] = 0;                  // fresh per launch (replay-safe)
    if (tid < 128) {                             // prefill x_0 (packed f16)
        float4 x0 = ((const float4*)x)[tid];
        ((uint2*)x_u[0])[tid] = make_uint2(pk2(x0.x, x0.y), pk2(x0.z, x0.w));
    }
    __syncthreads();

    // dot-thread mapping (waves 2..7): row 0..47, chunk 0..7
    const int idxd = tid - 128;
    const int row  = idxd >> 3;                  // 0..47
    const int c8   = idxd & 7;                   // == tid&7

    // ---- W_hh into registers, pre-staggered so loop indices are static ----
    uint32_t wreg[32];
    if (tid >= 128) {
        const uint32_t* wr = w_lds + (NR + row) * WPITCH + c8 * 32;
        #pragma unroll
        for (int i = 0; i < 32; ++i) wreg[i] = wr[(i + 4 * c8) & 31];
    }
    __syncthreads();

    float4 xp;
    if (tid < 128) xp = ((const float4*)(x + H))[tid];   // x_1
    float hprev = 0.0f;                          // own h (wave-2 lanes 0..15)

    for (int t = 0; t < SEQ_LEN; ++t) {
        const int par = t & 1, nxt = par ^ 1;

        if (tid < 128) {
            // issue x_{t+2} prefetch (hidden under the spin)
            int tq = t + 2; if (tq >= SEQ_LEN) tq = SEQ_LEN - 1;
            float4 xq = ((const float4*)(x + (size_t)tq * H))[tid];

            // ---- champion dependent spin on 4 tagged words (PROVEN) ----
            const uint32_t need = (uint32_t)t & 0xFFFFu;
            const uint32_t* base = tag32 + (size_t)par * H + 4 * tid;
            u32x4 v = poll16(base);
            while ((((v[0] ^ need) | (v[1] ^ need)) |
                    ((v[2] ^ need) | (v[3] ^ need))) & 0xFFFFu)
                v = poll16(base);
            // strip tags -> packed f16 pairs (pure bit ops)
            uint32_t p0 = (v[0] >> 16) | (v[1] & 0xFFFF0000u);
            uint32_t p1 = (v[2] >> 16) | (v[3] & 0xFFFF0000u);
            ((uint2*)h_u[par])[tid] = make_uint2(p0, p1);
            // release-add: h_u write ordered before counter bump
            __hip_atomic_fetch_add(&ccnt[tid >> 4], 1u,
                                   __ATOMIC_RELEASE, __HIP_MEMORY_SCOPE_WORKGROUP);
            // commit x_{t+1} (x_u[nxt] untouched by step-t readers)
            ((uint2*)x_u[nxt])[tid] = make_uint2(pk2(xp.x, xp.y), pk2(xp.z, xp.w));
            xp = xq;
            __syncthreads();   // B (the only barrier per step)
        } else {
            // ---- gi dots over x_u[par] (weights from LDS, fdot2) ----
            {
                const uint32_t* gw = w_lds + row * WPITCH + c8 * 32;
                const uint32_t* B  = &x_u[par][c8 * 32];
                float acc = 0.0f;
                #pragma unroll
                for (int i = 0; i < 32; ++i) {
                    int s = (i + 4 * c8) & 31;
                    acc = FDOT2(as_h2(gw[s]), as_h2(B[s]), acc);
                }
                acc += __shfl_xor(acc, 1);
                acc += __shfl_xor(acc, 2);
                acc += __shfl_xor(acc, 4);
                if (c8 == 0) sums_g[par][row] = acc + bsum_g[row];
            }

            // ---- chunk-sync: wait until my 16 h-regions are written ----
            {
                const uint32_t target = 16u * (uint32_t)(t + 1);
                while (__hip_atomic_load(&ccnt[c8], __ATOMIC_ACQUIRE,
                                         __HIP_MEMORY_SCOPE_WORKGROUP) < target) {}
            }

            // ---- hh dots over h_u[par] (weights from registers, fdot2) ----
            {
                const uint32_t* B = &h_u[par][c8 * 32];
                float acc = 0.0f;
                #pragma unroll
                for (int i = 0; i < 32; ++i) {
                    int s = (i + 4 * c8) & 31;
                    acc = FDOT2(as_h2(wreg[i]), as_h2(B[s]), acc);
                }
                acc += __shfl_xor(acc, 1);
                acc += __shfl_xor(acc, 2);
                acc += __shfl_xor(acc, 4);
                if (c8 == 0) sums_h[par][row] = acc + bsum_h[row];
            }
            __syncthreads();   // B

            // ---- gates + publish: wave 2 only (lanes 0..15 compute, 0..7 store u64) ----
            if (tid < 192) {
                int j = tid & 63;
                uint32_t pk = 0;
                float hnew = 0.0f;
                if (j < 16) {
                    float sg0 = sums_g[par][j],      sg1 = sums_g[par][16 + j], sg2 = sums_g[par][32 + j];
                    float sh0 = sums_h[par][j],      sh1 = sums_h[par][16 + j], sh2 = sums_h[par][32 + j];
                    float r_ = 1.0f / (1.0f + __expf(-(sg0 + sh0)));
                    float z_ = 1.0f / (1.0f + __expf(-(sg1 + sh1)));
                    float a  = sg2 + r_ * sh2;
                    a = fminf(12.0f, fmaxf(-12.0f, a));
                    float e2 = __expf(2.0f * a);
                    float n_ = (e2 - 1.0f) / (e2 + 1.0f);
                    hnew = (1.0f - z_) * n_ + z_ * hprev;
                    hprev = hnew;
                    pk = ((uint32_t)__half_as_ushort(__float2half(hnew)) << 16)
                       | ((uint32_t)(t + 1) & 0xFFFFu);
                }
                uint32_t lo = __shfl(pk, 2 * (j & 31));
                uint32_t hi = __shfl(pk, 2 * (j & 31) + 1);
                if (j < 8) {
                    u64* pb = (u64*)(tag32 + (size_t)nxt * H) + wg * 8 + j;
                    ST_AG(pb, ((u64)hi << 32) | (u64)lo);
                }
                if (j < 16) out[(size_t)t * H + j0 + j] = hnew;
            }
            // waves 3..7 proceed straight to next gi; wave 2 joins after publish
        }
    }
}

extern "C" void kernel_launch(void* const* d_in, const int* in_sizes, int n_in,
                              void* d_out, int out_size, void* d_ws, size_t ws_size,
                              hipStream_t stream) {
    const float* x   = (const float*)d_in[0];
    const float* Wih = (const float*)d_in[1];
    const float* Whh = (const float*)d_in[2];
    const float* bih = (const float*)d_in[3];
    const float* bhh = (const float*)d_in[4];
    float* out = (float*)d_out;
    uint32_t* tag32 = (uint32_t*)d_ws;           // 4 KB exchange

    gru_init<<<2, 512, 0, stream>>>(tag32);
    gru_main<<<NWG, T, 0, stream>>>(x, Wih, Whh, bih, bhh, out, tag32);
}

// Round 16
// 25258.618 us; speedup vs baseline: 1.2299x; 1.0970x over previous
//
#include <hip/hip_runtime.h>
#include <hip/hip_fp16.h>
#include <stdint.h>

#define SEQ_LEN 16384
#define H       512
#define NWG     32      // WG k owns h[16k..16k+16)
#define HK      16
#define T       512
#define NR      48      // rows per matrix per WG (3 gates x 16)
#define WPITCH  257     // uint32 pitch per weight row (256 data + 1 pad)

typedef unsigned long long u64;
typedef _Float16 h2 __attribute__((ext_vector_type(2)));
typedef unsigned int u32x4 __attribute__((ext_vector_type(4)));

#define LD_AG(p)   __hip_atomic_load((p),      __ATOMIC_RELAXED, __HIP_MEMORY_SCOPE_AGENT)
#define ST_AG(p,v) __hip_atomic_store((p),(v), __ATOMIC_RELAXED, __HIP_MEMORY_SCOPE_AGENT)

__device__ __forceinline__ h2 as_h2(uint32_t u) {
    union { uint32_t u; h2 h; } c; c.u = u; return c.h;
}

#if defined(__has_builtin)
#if __has_builtin(__builtin_amdgcn_fdot2)
#define FDOT2(a, b, c) __builtin_amdgcn_fdot2((a), (b), (c), false)
#endif
#endif
#ifndef FDOT2
__device__ __forceinline__ float fdot2_sw(h2 a, h2 b, float c) {
    return fmaf((float)a.x, (float)b.x, fmaf((float)a.y, (float)b.y, c));
}
#define FDOT2(a, b, c) fdot2_sw((a), (b), (c))
#endif

__device__ __forceinline__ uint32_t pk2(float a, float b) {
    return (uint32_t)__half_as_ushort(__float2half(a)) |
           ((uint32_t)__half_as_ushort(__float2half(b)) << 16);
}

// champion 16B poll: one dwordx4, L1/L2-bypassed, dependent spin (PROVEN)
__device__ __forceinline__ u32x4 poll16(const uint32_t* p) {
    u32x4 v;
    asm volatile("global_load_dwordx4 %0, %1, off sc0 sc1\n\t"
                 "s_waitcnt vmcnt(0)"
                 : "=v"(v) : "v"(p) : "memory");
    return v;
}

// exchange word: [f16 value (hi 16) | step tag (lo 16)]
__global__ void gru_init(uint32_t* __restrict__ tag32) {
    int i = blockIdx.x * blockDim.x + threadIdx.x;
    if (i < H)            ST_AG(&tag32[i], 0u);        // h0 = 0, tag 0
    else if (i < 2 * H)   ST_AG(&tag32[i], 0xFFFFu);   // invalid tag
}

__launch_bounds__(T, 1)
__global__ void gru_main(const float* __restrict__ x,
                         const float* __restrict__ Wih,
                         const float* __restrict__ Whh,
                         const float* __restrict__ bih,
                         const float* __restrict__ bhh,
                         float* __restrict__ out,
                         uint32_t* __restrict__ tag32)
{
    const int wg  = blockIdx.x;
    const int tid = threadIdx.x;
    const int j0  = wg * HK;

    __shared__ uint32_t w_lds[2 * NR * WPITCH];  // rows 0..47 W_ih, 48..95 W_hh (f16 pairs)
    __shared__ uint32_t x_u[2][H / 2];           // packed f16x2 x
    __shared__ uint32_t h_u[2][H / 2];           // packed f16x2 h
    __shared__ float    sums_g[2][NR];
    __shared__ float    sums_h[2][NR];
    __shared__ float    bsum_g[NR];
    __shared__ float    bsum_h[NR];

    __half* wh = (__half*)w_lds;                 // half pitch = 2*WPITCH

    // ---- prologue: stage weights f32 -> f16 LDS ----
    for (int idx = tid; idx < 2 * NR * H; idx += T) {
        int r  = idx >> 9;                       // 0..95
        int k  = idx & (H - 1);
        int rr = (r < NR) ? r : r - NR;
        int g  = rr >> 4;
        int jj = rr & 15;
        int grow = g * H + j0 + jj;
        float w = (r < NR) ? Wih[(size_t)grow * H + k] : Whh[(size_t)grow * H + k];
        wh[r * (2 * WPITCH) + k] = __float2half(w);
    }
    if (tid < NR) {
        int g  = tid >> 4;
        int jj = tid & 15;
        int grow = g * H + j0 + jj;
        bsum_g[tid] = (g == 2) ? bih[grow] : (bih[grow] + bhh[grow]);
        bsum_h[tid] = (g == 2) ? bhh[grow] : 0.0f;
    }
    if (tid < 128) {                             // prefill x_0 (packed f16)
        float4 x0 = ((const float4*)x)[tid];
        ((uint2*)x_u[0])[tid] = make_uint2(pk2(x0.x, x0.y), pk2(x0.z, x0.w));
    }
    __syncthreads();

    // dot-thread mapping (waves 2..7): row 0..47, chunk 0..7
    const int idxd = tid - 128;
    const int row  = idxd >> 3;                  // 0..47
    const int c8   = idxd & 7;                   // == tid&7

    // ---- W_hh into registers, pre-staggered so loop indices are static ----
    uint32_t wreg[32];
    if (tid >= 128) {
        const uint32_t* wr = w_lds + (NR + row) * WPITCH + c8 * 32;
        #pragma unroll
        for (int i = 0; i < 32; ++i) wreg[i] = wr[(i + 4 * c8) & 31];
    }
    __syncthreads();

    float4 xp;
    if (tid < 128) xp = ((const float4*)(x + H))[tid];   // x_1
    float hprev = 0.0f;                          // own h (wave-2 lanes 0..15)

    for (int t = 0; t < SEQ_LEN; ++t) {
        const int par = t & 1, nxt = par ^ 1;

        if (tid < 128) {
            // issue x_{t+2} prefetch (hidden under the spin)
            int tq = t + 2; if (tq >= SEQ_LEN) tq = SEQ_LEN - 1;
            float4 xq = ((const float4*)(x + (size_t)tq * H))[tid];

            // ---- champion tight dependent spin on 4 tagged words ----
            const uint32_t need = (uint32_t)t & 0xFFFFu;
            const uint32_t* base = tag32 + (size_t)par * H + 4 * tid;
            u32x4 v = poll16(base);
            while ((((v[0] ^ need) | (v[1] ^ need)) |
                    ((v[2] ^ need) | (v[3] ^ need))) & 0xFFFFu)
                v = poll16(base);
            // strip tags -> packed f16 pairs (pure bit ops)
            uint32_t p0 = (v[0] >> 16) | (v[1] & 0xFFFF0000u);
            uint32_t p1 = (v[2] >> 16) | (v[3] & 0xFFFF0000u);
            ((uint2*)h_u[par])[tid] = make_uint2(p0, p1);

            __syncthreads();   // A: h_u[par] + sums_g[par] ready
            // commit x_{t+1} as packed f16 (off critical path for dotters)
            ((uint2*)x_u[nxt])[tid] = make_uint2(pk2(xp.x, xp.y), pk2(xp.z, xp.w));
            xp = xq;
            __syncthreads();   // B: sums_h[par] + x_u[nxt] ready
            // pollers immediately proceed to next step's spin
        } else {
            // ---- gi dots over x_u[par] (weights from LDS, fdot2) ----
            {
                const uint32_t* gw = w_lds + row * WPITCH + c8 * 32;
                const uint32_t* B  = &x_u[par][c8 * 32];
                float acc = 0.0f;
                #pragma unroll
                for (int i = 0; i < 32; ++i) {
                    int s = (i + 4 * c8) & 31;
                    acc = FDOT2(as_h2(gw[s]), as_h2(B[s]), acc);
                }
                acc += __shfl_xor(acc, 1);
                acc += __shfl_xor(acc, 2);
                acc += __shfl_xor(acc, 4);
                if (c8 == 0) sums_g[par][row] = acc + bsum_g[row];
            }
            __syncthreads();   // A

            // ---- hh dots over h_u[par] (weights from registers, fdot2) ----
            {
                const uint32_t* B = &h_u[par][c8 * 32];
                float acc = 0.0f;
                #pragma unroll
                for (int i = 0; i < 32; ++i) {
                    int s = (i + 4 * c8) & 31;
                    acc = FDOT2(as_h2(wreg[i]), as_h2(B[s]), acc);
                }
                acc += __shfl_xor(acc, 1);
                acc += __shfl_xor(acc, 2);
                acc += __shfl_xor(acc, 4);
                if (c8 == 0) sums_h[par][row] = acc + bsum_h[row];
            }
            __syncthreads();   // B

            // ---- gates + publish: wave 2, lanes 0..15; direct u32 stores ----
            if (tid < 192) {
                int j = tid & 63;
                if (j < 16) {
                    float sg0 = sums_g[par][j],      sg1 = sums_g[par][16 + j], sg2 = sums_g[par][32 + j];
                    float sh0 = sums_h[par][j],      sh1 = sums_h[par][16 + j], sh2 = sums_h[par][32 + j];
                    float r_ = 1.0f / (1.0f + __expf(-(sg0 + sh0)));
                    float z_ = 1.0f / (1.0f + __expf(-(sg1 + sh1)));
                    float a  = sg2 + r_ * sh2;
                    a = fminf(12.0f, fmaxf(-12.0f, a));
                    float e2 = __expf(2.0f * a);
                    float n_ = (e2 - 1.0f) / (e2 + 1.0f);
                    float hnew = (1.0f - z_) * n_ + z_ * hprev;
                    hprev = hnew;
                    uint32_t pk = ((uint32_t)__half_as_ushort(__float2half(hnew)) << 16)
                                | ((uint32_t)(t + 1) & 0xFFFFu);
                    // 16 lanes store 16 consecutive dwords = one 64B line, coalesced;
                    // no shuffle packing on the critical path before the store issues
                    ST_AG(&tag32[(size_t)nxt * H + j0 + j], pk);
                    out[(size_t)t * H + j0 + j] = hnew;   // off critical path
                }
            }
            // wave 2 proceeds to next step's gi (lateness absorbed at barrier A)
        }
    }
}

extern "C" void kernel_launch(void* const* d_in, const int* in_sizes, int n_in,
                              void* d_out, int out_size, void* d_ws, size_t ws_size,
                              hipStream_t stream) {
    const float* x   = (const float*)d_in[0];
    const float* Wih = (const float*)d_in[1];
    const float* Whh = (const float*)d_in[2];
    const float* bih = (const float*)d_in[3];
    const float* bhh = (const float*)d_in[4];
    float* out = (float*)d_out;
    uint32_t* tag32 = (uint32_t*)d_ws;           // 4 KB exchange

    gru_init<<<2, 512, 0, stream>>>(tag32);
    gru_main<<<NWG, T, 0, stream>>>(x, Wih, Whh, bih, bhh, out, tag32);
}